// Round 2
// baseline (2390.271 us; speedup 1.0000x reference)
//
#include <hip/hip_runtime.h>

// Problem constants
#define B_  4096
#define T_  64
#define D_  256
#define E_  128
#define H_  256
#define KS_ 384    // E + H

typedef __attribute__((ext_vector_type(8))) short short8;
typedef __attribute__((ext_vector_type(4))) float f32x4;

__device__ inline unsigned short f2bf(float f){
  unsigned u = __float_as_uint(f);
  u += 0x7FFFu + ((u >> 16) & 1u);   // RNE
  return (unsigned short)(u >> 16);
}
__device__ inline float sigm_(float x){ return __fdividef(1.f, 1.f + __expf(-x)); }
__device__ inline float tanh_(float x){
  float e = __expf(2.f * fminf(fmaxf(x, -15.f), 15.f));
  return __fdividef(e - 1.f, e + 1.f);
}

// ---------------------------------------------------------------------------
// init: Wcat'[g'][k] bf16, gate-interleaved rows g' = h*4 + q (q = torch gate
// i,f,g,o), k = [e(128) | h(256)]; biasc'[g'] = b_ih[g] + b_hh[g].
// grid 1024 blocks x 384 threads (one block per g' row).
// ---------------------------------------------------------------------------
__global__ __launch_bounds__(384) void init_kernel(
    const float* __restrict__ W_ih, const float* __restrict__ b_ih,
    const float* __restrict__ W_hh, const float* __restrict__ b_hh,
    unsigned short* __restrict__ Wcat, float* __restrict__ biasc){
  const int gp = blockIdx.x;          // g'
  const int k  = threadIdx.x;
  const int h  = gp >> 2, q = gp & 3;
  const int g  = q * H_ + h;          // torch row
  float v = (k < E_) ? W_ih[g*E_ + k] : W_hh[g*H_ + (k - E_)];
  Wcat[(size_t)gp*KS_ + k] = f2bf(v);
  if (k == 0) biasc[gp] = b_ih[g] + b_hh[g];
}

// ---------------------------------------------------------------------------
// encT[t][b][e] = bf16(tanh(x @ W_enc^T + b_enc)), MFMA 16x16x32 bf16.
// block tile 128(M over bt) x 128(N=E), BK=64, 4 waves each 32x128. grid 2048.
// ---------------------------------------------------------------------------
__global__ __launch_bounds__(256) void enc_kernel(
    const float* __restrict__ x, const float* __restrict__ W_enc,
    const float* __restrict__ b_enc, unsigned short* __restrict__ encT){
  __shared__ unsigned short As[128*64];
  __shared__ unsigned short Bs[128*64];
  __shared__ float bes[128];
  const int tid = threadIdx.x;
  const int lane = tid & 63, w = tid >> 6;
  const int l15 = lane & 15, lq = lane >> 4;
  const int m0 = blockIdx.x * 128;
  if (tid < 128) bes[tid] = b_enc[tid];

  f32x4 acc[16];
  #pragma unroll
  for (int i=0;i<16;i++) acc[i] = (f32x4)0.f;

  for (int kc = 0; kc < 4; ++kc){
    const int kb = kc*64;
    __syncthreads();
    #pragma unroll
    for (int i=0;i<4;i++){
      int u = i*256 + tid; int r = u>>3, s = u&7;
      const float* sp = x + (size_t)(m0+r)*D_ + kb + s*8;
      float4 v0 = *(const float4*)sp;
      float4 v1 = *(const float4*)(sp+4);
      short8 pk;
      pk[0]=(short)f2bf(v0.x); pk[1]=(short)f2bf(v0.y); pk[2]=(short)f2bf(v0.z); pk[3]=(short)f2bf(v0.w);
      pk[4]=(short)f2bf(v1.x); pk[5]=(short)f2bf(v1.y); pk[6]=(short)f2bf(v1.z); pk[7]=(short)f2bf(v1.w);
      int off = (r*128 + s*16) ^ ((r&7)<<4);
      *(short8*)((char*)As + off) = pk;
    }
    #pragma unroll
    for (int i=0;i<4;i++){
      int u = i*256 + tid; int r = u>>3, s = u&7;
      const float* sp = W_enc + (size_t)r*D_ + kb + s*8;
      float4 v0 = *(const float4*)sp;
      float4 v1 = *(const float4*)(sp+4);
      short8 pk;
      pk[0]=(short)f2bf(v0.x); pk[1]=(short)f2bf(v0.y); pk[2]=(short)f2bf(v0.z); pk[3]=(short)f2bf(v0.w);
      pk[4]=(short)f2bf(v1.x); pk[5]=(short)f2bf(v1.y); pk[6]=(short)f2bf(v1.z); pk[7]=(short)f2bf(v1.w);
      int off = (r*128 + s*16) ^ ((r&7)<<4);
      *(short8*)((char*)Bs + off) = pk;
    }
    __syncthreads();
    #pragma unroll
    for (int kk=0;kk<2;kk++){
      short8 af[2];
      #pragma unroll
      for (int mi=0;mi<2;mi++){
        int r = 32*w + mi*16 + l15;
        int off = (r*128 + kk*64 + lq*16) ^ ((r&7)<<4);
        af[mi] = *(const short8*)((const char*)As + off);
      }
      #pragma unroll
      for (int nf=0;nf<8;nf++){
        int r = nf*16 + l15;
        int off = (r*128 + kk*64 + lq*16) ^ ((r&7)<<4);
        short8 bfr = *(const short8*)((const char*)Bs + off);
        #pragma unroll
        for (int mi=0;mi<2;mi++)
          acc[mi*8+nf] = __builtin_amdgcn_mfma_f32_16x16x32_bf16(af[mi], bfr, acc[mi*8+nf], 0,0,0);
      }
    }
  }
  // epilogue: tanh + bias, store bf16 transposed [t][b][e]
  #pragma unroll
  for (int mi=0;mi<2;mi++){
    #pragma unroll
    for (int nf=0;nf<8;nf++){
      int col = nf*16 + l15;
      float be = bes[col];
      #pragma unroll
      for (int j=0;j<4;j++){
        int bt = m0 + 32*w + mi*16 + lq*4 + j;
        int b = bt >> 6, tt = bt & 63;
        encT[((size_t)tt*B_ + b)*E_ + col] = f2bf(tanh_(acc[mi*8+nf][j] + be));
      }
    }
  }
}

// ---------------------------------------------------------------------------
// Persistent LSTM recurrence. 128 blocks x 512 threads (8 waves).
// Block owns 32 batch rows for all 64 steps; h in LDS (swizzled), c in regs.
// Wave w owns h-slice [w*32, w*32+32) x 4 gates (128 gate cols, g'=h*4+q).
// Per step: gates = [enc_t | h] @ Wcat'^T ; K=384 (12 k-chunks of 32).
// ---------------------------------------------------------------------------
__global__ __launch_bounds__(512) void rec_kernel(
    const unsigned short* __restrict__ encT,
    const unsigned short* __restrict__ Wcat,
    const float* __restrict__ biasc,
    const float* __restrict__ x,
    float* __restrict__ out_hn,
    float* __restrict__ out_ldt){
  __shared__ unsigned short hbuf[32*256];   // [row][h] bf16, XOR-swizzled, 16 KB
  char* hbc = (char*)hbuf;
  const int tid = threadIdx.x, lane = tid & 63, w = tid >> 6;
  const int l15 = lane & 15, lq = lane >> 4;
  const int b0 = blockIdx.x * 32;
  const int hw = w * 32;

  // per-lane biases for the 8 (hh,q) gate columns
  float bs[8];
  #pragma unroll
  for (int hh=0;hh<2;hh++)
    #pragma unroll
    for (int q=0;q<4;q++)
      bs[hh*4+q] = biasc[(hw + hh*16 + l15)*4 + q];

  // W fragment base pointers (per (hh,q)); per-kk offsets fold into imm
  const unsigned short* wp[8];
  #pragma unroll
  for (int hh=0;hh<2;hh++)
    #pragma unroll
    for (int q=0;q<4;q++)
      wp[hh*4+q] = Wcat + (size_t)((hw + hh*16 + l15)*4 + q)*KS_ + lq*8;

  // enc A-frag row bases (element offsets; add t*B_*E_ per step)
  const unsigned short* ep[2];
  #pragma unroll
  for (int mi=0;mi<2;mi++)
    ep[mi] = encT + (size_t)(b0 + mi*16 + l15)*E_ + lq*8;

  // LDS A-frag read offset components
  int ra[2], sa[2];
  #pragma unroll
  for (int mi=0;mi<2;mi++){
    int r = mi*16 + l15;
    ra[mi] = r*512 + lq*16;
    sa[mi] = (r & 7) << 4;
  }

  float creg[16];                 // c state: [mi][hh][j]
  #pragma unroll
  for (int i=0;i<16;i++) creg[i] = 0.f;
  for (int i=tid; i<32*256; i+=512) hbuf[i] = 0;   // h0 = 0
  __syncthreads();

  for (int t=0; t<T_; ++t){
    f32x4 acc[2][8];              // [mi][hh*4+q]
    #pragma unroll
    for (int mi=0;mi<2;mi++)
      #pragma unroll
      for (int u=0;u<8;u++) acc[mi][u] = (f32x4)0.f;

    const size_t toff = (size_t)t * B_ * E_;
    short8 ae[2][4];
    #pragma unroll
    for (int mi=0;mi<2;mi++)
      #pragma unroll
      for (int kk=0;kk<4;kk++)
        ae[mi][kk] = *(const short8*)(ep[mi] + toff + kk*32);

    #pragma unroll
    for (int kk=0;kk<12;kk++){
      short8 bfr[8];
      #pragma unroll
      for (int u=0;u<8;u++) bfr[u] = *(const short8*)(wp[u] + kk*32);
      short8 af[2];
      if (kk < 4){ af[0] = ae[0][kk]; af[1] = ae[1][kk]; }
      else {
        #pragma unroll
        for (int mi=0;mi<2;mi++)
          af[mi] = *(const short8*)(hbc + ((ra[mi] + (kk-4)*64) ^ sa[mi]));
      }
      #pragma unroll
      for (int mi=0;mi<2;mi++)
        #pragma unroll
        for (int u=0;u<8;u++)
          acc[mi][u] = __builtin_amdgcn_mfma_f32_16x16x32_bf16(af[mi], bfr[u], acc[mi][u], 0,0,0);
    }
    __syncthreads();   // all waves done reading hbuf (step t)

    #pragma unroll
    for (int mi=0;mi<2;mi++){
      #pragma unroll
      for (int hh=0;hh<2;hh++){
        #pragma unroll
        for (int j=0;j<4;j++){
          float gi = sigm_(acc[mi][hh*4+0][j] + bs[hh*4+0]);
          float gf = sigm_(acc[mi][hh*4+1][j] + bs[hh*4+1]);
          float gg = tanh_(acc[mi][hh*4+2][j] + bs[hh*4+2]);
          float go = sigm_(acc[mi][hh*4+3][j] + bs[hh*4+3]);
          int ci = mi*8 + hh*4 + j;
          float cn = gf*creg[ci] + gi*gg;
          creg[ci] = cn;
          float hn = go * tanh_(cn);
          int row  = mi*16 + lq*4 + j;
          int hcol = hw + hh*16 + l15;
          *(unsigned short*)(hbc + ((row*512 + hcol*2) ^ ((row&7)<<4))) = f2bf(hn);
          int b = b0 + row;
          if (t < T_-1){
            float xv = x[((size_t)b*T_ + t+1)*D_ + hcol];
            out_ldt[((size_t)b*T_ + t)*H_ + hcol] = fabsf(hn - xv);
          } else {
            out_hn[(size_t)b*H_ + hcol] = hn;
          }
        }
      }
    }
    __syncthreads();   // h(t+1) visible before next step's reads
  }
}

// ---------------------------------------------------------------------------
// finalize: loss[b] = sum_t sqrt(sum_h ad^2)/63 ; loss_dim = sum_t ad/63 ;
// zero the t=T-1 slice of loss_dim_t. One wave per batch row. grid 1024.
// ---------------------------------------------------------------------------
__global__ __launch_bounds__(256) void final_kernel(
    float* __restrict__ out_loss, float* __restrict__ out_ldim,
    float* __restrict__ out_ldt){
  const int w = threadIdx.x >> 6, lane = threadIdx.x & 63;
  const int b = blockIdx.x*4 + w;
  const float* base = out_ldt + (size_t)b*(T_*H_);
  float adx=0.f, ady=0.f, adz=0.f, adw=0.f;
  float lacc = 0.f;
  for (int t=0;t<T_-1;++t){
    float4 v = *(const float4*)(base + t*H_ + lane*4);
    adx += v.x; ady += v.y; adz += v.z; adw += v.w;
    float s = v.x*v.x + v.y*v.y + v.z*v.z + v.w*v.w;
    #pragma unroll
    for (int off=32; off; off>>=1) s += __shfl_xor(s, off);
    lacc += sqrtf(s);
  }
  const float inv = 1.f/(float)(T_-1);
  float4 o; o.x=adx*inv; o.y=ady*inv; o.z=adz*inv; o.w=adw*inv;
  *(float4*)(out_ldim + (size_t)b*H_ + lane*4) = o;
  float4 z; z.x=0.f; z.y=0.f; z.z=0.f; z.w=0.f;
  *(float4*)(out_ldt + (size_t)b*(T_*H_) + (size_t)(T_-1)*H_ + lane*4) = z;
  if (lane==0) out_loss[b] = lacc*inv;
}

// ---------------------------------------------------------------------------
extern "C" void kernel_launch(void* const* d_in, const int* in_sizes, int n_in,
                              void* d_out, int out_size, void* d_ws, size_t ws_size,
                              hipStream_t stream){
  const float* x     = (const float*)d_in[0];
  const float* W_enc = (const float*)d_in[1];
  const float* b_enc = (const float*)d_in[2];
  const float* W_ih  = (const float*)d_in[3];
  const float* b_ih  = (const float*)d_in[4];
  const float* W_hh  = (const float*)d_in[5];
  const float* b_hh  = (const float*)d_in[6];

  // workspace: encT 64 MB | Wcat 768 KB | biasc 4 KB
  char* ws = (char*)d_ws;
  unsigned short* encT  = (unsigned short*)(ws);                 // 67,108,864 B
  unsigned short* Wcat  = (unsigned short*)(ws + 67108864);      //    786,432 B
  float*          biasc = (float*)        (ws + 67895296);       //      4,096 B

  float* out_hn   = (float*)d_out;
  float* out_loss = out_hn  + (size_t)B_*H_;
  float* out_ldim = out_loss + B_;
  float* out_ldt  = out_ldim + (size_t)B_*H_;

  init_kernel<<<1024, 384, 0, stream>>>(W_ih, b_ih, W_hh, b_hh, Wcat, biasc);
  enc_kernel<<<2048, 256, 0, stream>>>(x, W_enc, b_enc, encT);
  rec_kernel<<<128, 512, 0, stream>>>(encT, Wcat, biasc, x, out_hn, out_ldt);
  final_kernel<<<1024, 256, 0, stream>>>(out_loss, out_ldim, out_ldt);
}

// Round 4
// 1564.989 us; speedup vs baseline: 1.5273x; 1.5273x over previous
//
#include <hip/hip_runtime.h>

// Problem constants
#define B_  4096
#define T_  64
#define D_  256
#define E_  128
#define H_  256
#define KS_ 384    // E + H

typedef __attribute__((ext_vector_type(8))) short short8;
typedef __attribute__((ext_vector_type(4))) float f32x4;

__device__ inline unsigned short f2bf(float f){
  unsigned u = __float_as_uint(f);
  u += 0x7FFFu + ((u >> 16) & 1u);   // RNE
  return (unsigned short)(u >> 16);
}
__device__ inline float sigm_(float x){ return __fdividef(1.f, 1.f + __expf(-x)); }
__device__ inline float tanh_(float x){
  float e = __expf(2.f * fminf(fmaxf(x, -15.f), 15.f));
  return __fdividef(e - 1.f, e + 1.f);
}
__device__ inline short8 ntload8(const unsigned short* p){
  return __builtin_nontemporal_load((const short8*)p);
}
__device__ inline f32x4 ntload4f(const float* p){
  return __builtin_nontemporal_load((const f32x4*)p);
}

// ---------------------------------------------------------------------------
// init: pack weights into MFMA-fragment order.
// Wf index: frag = (w*12 + kk)*4 + q ; element = frag*512 + lane*8 + e
//   value = W'[(w*16 + (lane&15))*4 + q][kk*32 + (lane>>4)*8 + e]
//   W'[h*4+q][k] = k<128 ? W_ih[q*256+h][k] : W_hh[q*256+h][k-128]
// Also biasc[h*4+q] = b_ih[q*256+h] + b_hh[q*256+h].
// grid 1536 x 256 covers 393216 ushorts.
// ---------------------------------------------------------------------------
__global__ __launch_bounds__(256) void init_kernel(
    const float* __restrict__ W_ih, const float* __restrict__ b_ih,
    const float* __restrict__ W_hh, const float* __restrict__ b_hh,
    unsigned short* __restrict__ Wf, float* __restrict__ biasc){
  const int idx = blockIdx.x*256 + threadIdx.x;
  const int e    = idx & 7;
  const int lane = (idx >> 3) & 63;
  const int frag = idx >> 9;          // 0..767
  const int q    = frag & 3;
  const int fk   = frag >> 2;         // 0..191
  const int kk   = fk % 12;
  const int w    = fk / 12;
  const int h    = w*16 + (lane & 15);
  const int k    = kk*32 + (lane >> 4)*8 + e;
  const int g    = q*H_ + h;
  float v = (k < E_) ? W_ih[g*E_ + k] : W_hh[g*H_ + (k - E_)];
  Wf[idx] = f2bf(v);
  if (idx < 4*H_){
    int hh = idx >> 2, qq = idx & 3, gg = qq*H_ + hh;
    biasc[idx] = b_ih[gg] + b_hh[gg];
  }
}

// ---------------------------------------------------------------------------
// encT[t][b][e] = bf16(tanh(x @ W_enc^T + b_enc)), MFMA 16x16x32 bf16.
// block tile 128(M over bt) x 128(N=E), BK=64, 4 waves each 32x128. grid 2048.
// ---------------------------------------------------------------------------
__global__ __launch_bounds__(256) void enc_kernel(
    const float* __restrict__ x, const float* __restrict__ W_enc,
    const float* __restrict__ b_enc, unsigned short* __restrict__ encT){
  __shared__ unsigned short As[128*64];
  __shared__ unsigned short Bs[128*64];
  __shared__ float bes[128];
  const int tid = threadIdx.x;
  const int lane = tid & 63, w = tid >> 6;
  const int l15 = lane & 15, lq = lane >> 4;
  const int m0 = blockIdx.x * 128;
  if (tid < 128) bes[tid] = b_enc[tid];

  f32x4 acc[16];
  #pragma unroll
  for (int i=0;i<16;i++) acc[i] = (f32x4)0.f;

  for (int kc = 0; kc < 4; ++kc){
    const int kb = kc*64;
    __syncthreads();
    #pragma unroll
    for (int i=0;i<4;i++){
      int u = i*256 + tid; int r = u>>3, s = u&7;
      const float* sp = x + (size_t)(m0+r)*D_ + kb + s*8;
      f32x4 v0 = ntload4f(sp);
      f32x4 v1 = ntload4f(sp+4);
      short8 pk;
      pk[0]=(short)f2bf(v0[0]); pk[1]=(short)f2bf(v0[1]); pk[2]=(short)f2bf(v0[2]); pk[3]=(short)f2bf(v0[3]);
      pk[4]=(short)f2bf(v1[0]); pk[5]=(short)f2bf(v1[1]); pk[6]=(short)f2bf(v1[2]); pk[7]=(short)f2bf(v1[3]);
      int off = (r*128 + s*16) ^ ((r&7)<<4);
      *(short8*)((char*)As + off) = pk;
    }
    #pragma unroll
    for (int i=0;i<4;i++){
      int u = i*256 + tid; int r = u>>3, s = u&7;
      const float* sp = W_enc + (size_t)r*D_ + kb + s*8;
      f32x4 v0 = *(const f32x4*)sp;
      f32x4 v1 = *(const f32x4*)(sp+4);
      short8 pk;
      pk[0]=(short)f2bf(v0[0]); pk[1]=(short)f2bf(v0[1]); pk[2]=(short)f2bf(v0[2]); pk[3]=(short)f2bf(v0[3]);
      pk[4]=(short)f2bf(v1[0]); pk[5]=(short)f2bf(v1[1]); pk[6]=(short)f2bf(v1[2]); pk[7]=(short)f2bf(v1[3]);
      int off = (r*128 + s*16) ^ ((r&7)<<4);
      *(short8*)((char*)Bs + off) = pk;
    }
    __syncthreads();
    #pragma unroll
    for (int kk=0;kk<2;kk++){
      short8 af[2];
      #pragma unroll
      for (int mi=0;mi<2;mi++){
        int r = 32*w + mi*16 + l15;
        int off = (r*128 + kk*64 + lq*16) ^ ((r&7)<<4);
        af[mi] = *(const short8*)((const char*)As + off);
      }
      #pragma unroll
      for (int nf=0;nf<8;nf++){
        int r = nf*16 + l15;
        int off = (r*128 + kk*64 + lq*16) ^ ((r&7)<<4);
        short8 bfr = *(const short8*)((const char*)Bs + off);
        #pragma unroll
        for (int mi=0;mi<2;mi++)
          acc[mi*8+nf] = __builtin_amdgcn_mfma_f32_16x16x32_bf16(af[mi], bfr, acc[mi*8+nf], 0,0,0);
      }
    }
  }
  #pragma unroll
  for (int mi=0;mi<2;mi++){
    #pragma unroll
    for (int nf=0;nf<8;nf++){
      int col = nf*16 + l15;
      float be = bes[col];
      #pragma unroll
      for (int j=0;j<4;j++){
        int bt = m0 + 32*w + mi*16 + lq*4 + j;
        int b = bt >> 6, tt = bt & 63;
        encT[((size_t)tt*B_ + b)*E_ + col] = f2bf(tanh_(acc[mi*8+nf][j] + be));
      }
    }
  }
}

// ---------------------------------------------------------------------------
// Persistent LSTM recurrence. 256 blocks x 1024 threads (16 waves).
// Block owns 16 batch rows for all 64 steps; h in LDS (dbuf, swizzled), c regs.
// Wave w owns h-dims [w*16, w*16+16) x 4 gates; weight frags pre-packed so
// every weight load is a coalesced 1KB wave load.
// ---------------------------------------------------------------------------
__global__ __launch_bounds__(1024, 4) void rec_kernel(
    const unsigned short* __restrict__ encT,
    const unsigned short* __restrict__ Wf,
    const float* __restrict__ biasc,
    const float* __restrict__ x,
    float* __restrict__ out_hn,
    float* __restrict__ out_ldt){
  __shared__ unsigned short hbuf[2][16*256];   // 2 x 8 KB, row stride 512B, swizzled
  const int tid = threadIdx.x, lane = tid & 63, w = tid >> 6;
  const int l15 = lane & 15, lq = lane >> 4;
  const int b0 = blockIdx.x * 16;
  const int hcol = w*16 + l15;

  const f32x4 bias = *(const f32x4*)(biasc + hcol*4);
  const unsigned short* wfb = Wf + (size_t)w*24576 + lane*8;   // + (kk*4+q)*512
  const unsigned short* ep  = encT + ((size_t)(b0 + l15))*E_ + lq*8;  // + t*B_*E_ + kk*32
  const int rdbyte = l15*512 + lq*16;
  const int rsw    = (l15 & 7) << 4;

  float creg[4] = {0.f,0.f,0.f,0.f};
  for (int i = tid; i < 16*256; i += 1024) hbuf[0][i] = 0;
  __syncthreads();

  short8 ae[4];
  #pragma unroll
  for (int kk=0;kk<4;kk++) ae[kk] = ntload8(ep + kk*32);

  for (int t=0; t<T_; ++t){
    char* rb = (char*)hbuf[t & 1];
    char* wb = (char*)hbuf[(t+1) & 1];

    // prefetch x values consumed by this step's pointwise
    float xv[4];
    if (t < T_-1){
      #pragma unroll
      for (int j=0;j<4;j++)
        xv[j] = __builtin_nontemporal_load(x + ((size_t)(b0+lq*4+j)*T_ + t+1)*D_ + hcol);
    }
    // prefetch next step's enc frags
    short8 aen[4];
    if (t < T_-1){
      #pragma unroll
      for (int kk=0;kk<4;kk++)
        aen[kk] = ntload8(ep + (size_t)(t+1)*B_*E_ + kk*32);
    }

    f32x4 acc[4];
    #pragma unroll
    for (int q=0;q<4;q++) acc[q] = (f32x4)0.f;

    #pragma unroll
    for (int kk=0;kk<12;kk++){
      short8 af;
      if (kk < 4) af = ae[kk];
      else        af = *(const short8*)(rb + ((rdbyte + (kk-4)*64) ^ rsw));
      #pragma unroll
      for (int q=0;q<4;q++){
        short8 bq = *(const short8*)(wfb + (kk*4+q)*512);
        acc[q] = __builtin_amdgcn_mfma_f32_16x16x32_bf16(af, bq, acc[q], 0,0,0);
      }
    }

    // pointwise update; lane owns (h=hcol, batch rows b0+lq*4+j)
    #pragma unroll
    for (int j=0;j<4;j++){
      float gi = sigm_(acc[0][j] + bias[0]);
      float gf = sigm_(acc[1][j] + bias[1]);
      float gg = tanh_(acc[2][j] + bias[2]);
      float go = sigm_(acc[3][j] + bias[3]);
      float cn = gf*creg[j] + gi*gg;
      creg[j] = cn;
      float hn = go * tanh_(cn);
      int row = lq*4 + j;
      *(unsigned short*)(wb + ((row*512 + hcol*2) ^ ((row&7)<<4))) = f2bf(hn);
      int b = b0 + row;
      if (t < T_-1){
        __builtin_nontemporal_store(fabsf(hn - xv[j]),
            out_ldt + ((size_t)b*T_ + t)*H_ + hcol);
      } else {
        __builtin_nontemporal_store(hn, out_hn + (size_t)b*H_ + hcol);
      }
    }
    __syncthreads();
    #pragma unroll
    for (int kk=0;kk<4;kk++) ae[kk] = aen[kk];
  }
}

// ---------------------------------------------------------------------------
// finalize: loss[b] = sum_t sqrt(sum_h ad^2)/63 ; loss_dim = sum_t ad/63 ;
// zero the t=T-1 slice of loss_dim_t. One wave per batch row. grid 1024.
// ---------------------------------------------------------------------------
__global__ __launch_bounds__(256) void final_kernel(
    float* __restrict__ out_loss, float* __restrict__ out_ldim,
    float* __restrict__ out_ldt){
  const int w = threadIdx.x >> 6, lane = threadIdx.x & 63;
  const int b = blockIdx.x*4 + w;
  const float* base = out_ldt + (size_t)b*(T_*H_);
  float adx=0.f, ady=0.f, adz=0.f, adw=0.f;
  float lacc = 0.f;
  for (int t=0;t<T_-1;++t){
    f32x4 v = ntload4f(base + t*H_ + lane*4);
    adx += v[0]; ady += v[1]; adz += v[2]; adw += v[3];
    float s = v[0]*v[0] + v[1]*v[1] + v[2]*v[2] + v[3]*v[3];
    #pragma unroll
    for (int off=32; off; off>>=1) s += __shfl_xor(s, off);
    lacc += sqrtf(s);
  }
  const float inv = 1.f/(float)(T_-1);
  f32x4 o; o[0]=adx*inv; o[1]=ady*inv; o[2]=adz*inv; o[3]=adw*inv;
  *(f32x4*)(out_ldim + (size_t)b*H_ + lane*4) = o;
  f32x4 z = (f32x4)0.f;
  *(f32x4*)(out_ldt + (size_t)b*(T_*H_) + (size_t)(T_-1)*H_ + lane*4) = z;
  if (lane==0) out_loss[b] = lacc*inv;
}

// ---------------------------------------------------------------------------
extern "C" void kernel_launch(void* const* d_in, const int* in_sizes, int n_in,
                              void* d_out, int out_size, void* d_ws, size_t ws_size,
                              hipStream_t stream){
  const float* x     = (const float*)d_in[0];
  const float* W_enc = (const float*)d_in[1];
  const float* b_enc = (const float*)d_in[2];
  const float* W_ih  = (const float*)d_in[3];
  const float* b_ih  = (const float*)d_in[4];
  const float* W_hh  = (const float*)d_in[5];
  const float* b_hh  = (const float*)d_in[6];

  // workspace: encT 64 MB | Wf 768 KB | biasc 4 KB
  char* ws = (char*)d_ws;
  unsigned short* encT  = (unsigned short*)(ws);                 // 67,108,864 B
  unsigned short* Wf    = (unsigned short*)(ws + 67108864);      //    786,432 B
  float*          biasc = (float*)        (ws + 67895296);       //      4,096 B

  float* out_hn   = (float*)d_out;
  float* out_loss = out_hn  + (size_t)B_*H_;
  float* out_ldim = out_loss + B_;
  float* out_ldt  = out_ldim + (size_t)B_*H_;

  init_kernel<<<1536, 256, 0, stream>>>(W_ih, b_ih, W_hh, b_hh, Wf, biasc);
  enc_kernel<<<2048, 256, 0, stream>>>(x, W_enc, b_enc, encT);
  rec_kernel<<<256, 1024, 0, stream>>>(encT, Wf, biasc, x, out_hn, out_ldt);
  final_kernel<<<1024, 256, 0, stream>>>(out_loss, out_ldim, out_ldt);
}